// Round 1
// baseline (15855.695 us; speedup 1.0000x reference)
//
#include <hip/hip_runtime.h>

// RetinaNet head, fp32 baseline.
// Tower conv: 3x3, C=256->256, ReLU. Block = 256 threads:
//   8x8 spatial tile x 32 output channels; each thread = 1 co x 8-pixel row.
//   ci staged in chunks of 8 into LDS (halo 10x10 padded to stride 12 for
//   b128 reads; weights 9 padded to 12). Bank-conflict free (12k mod 32 distinct).
// Final conv: same structure, co bounds-checked, writes permuted output.

#define CI_CHUNK 8
#define CO_TILE 32
#define TS 8

template <bool RELU>
__global__ __launch_bounds__(256) void conv_tower(
    const float* __restrict__ x, const float* __restrict__ w,
    const float* __restrict__ b, float* __restrict__ y,
    int H, int W, int tilesX) {
  __shared__ float xs[CI_CHUNK][10 * 12];
  __shared__ float ws[CI_CHUNK][CO_TILE * 12];
  const int C = 256;
  const int t = threadIdx.x;
  const int tile = blockIdx.x;
  const int co_base = blockIdx.y * CO_TILE;
  const int n = blockIdx.z;
  const int ty = tile / tilesX, tx = tile - ty * tilesX;
  const int h0 = ty * TS, w0 = tx * TS;
  const int co_l = t >> 3;  // 0..31
  const int row = t & 7;    // 0..7
  const int co = co_base + co_l;

  float acc[8];
#pragma unroll
  for (int i = 0; i < 8; i++) acc[i] = 0.f;

  const float* xn = x + (size_t)n * C * H * W;

  for (int cb = 0; cb < C; cb += CI_CHUNK) {
    // stage input halo: CI_CHUNK * 10 * 10 elements (zero-pad OOB)
    for (int i = t; i < CI_CHUNK * 100; i += 256) {
      int ci = i / 100;
      int p = i - ci * 100;
      int r = p / 10;
      int c = p - r * 10;
      int hh = h0 - 1 + r, ww = w0 - 1 + c;
      float v = 0.f;
      if (hh >= 0 && hh < H && ww >= 0 && ww < W)
        v = xn[(size_t)(cb + ci) * H * W + hh * W + ww];
      xs[ci][r * 12 + c] = v;
    }
    // stage weights: CI_CHUNK * CO_TILE * 9
    for (int i = t; i < CI_CHUNK * CO_TILE * 9; i += 256) {
      int ci = i / (CO_TILE * 9);
      int p = i - ci * (CO_TILE * 9);
      int c2 = p / 9;
      int j = p - c2 * 9;
      ws[ci][c2 * 12 + j] =
          w[((size_t)(co_base + c2) * C + cb + ci) * 9 + j];
    }
    __syncthreads();
#pragma unroll
    for (int ci = 0; ci < CI_CHUNK; ci++) {
      const float4* wp = (const float4*)&ws[ci][co_l * 12];
      float4 w0v = wp[0], w1v = wp[1], w2v = wp[2];
      float wr[9] = {w0v.x, w0v.y, w0v.z, w0v.w, w1v.x, w1v.y, w1v.z, w1v.w, w2v.x};
#pragma unroll
      for (int r = 0; r < 3; r++) {
        const float4* xp = (const float4*)&xs[ci][(row + r) * 12];
        float4 a0 = xp[0], a1 = xp[1], a2 = xp[2];
        float xv[12] = {a0.x, a0.y, a0.z, a0.w, a1.x, a1.y,
                        a1.z, a1.w, a2.x, a2.y, a2.z, a2.w};
#pragma unroll
        for (int c = 0; c < 8; c++) {
          acc[c] = fmaf(xv[c + 0], wr[r * 3 + 0], acc[c]);
          acc[c] = fmaf(xv[c + 1], wr[r * 3 + 1], acc[c]);
          acc[c] = fmaf(xv[c + 2], wr[r * 3 + 2], acc[c]);
        }
      }
    }
    __syncthreads();
  }

  const float bias = b[co];
#pragma unroll
  for (int c = 0; c < 8; c++) {
    int hh = h0 + row, ww = w0 + c;
    if (hh < H && ww < W) {
      float v = acc[c] + bias;
      if (RELU) v = fmaxf(v, 0.f);
      y[((size_t)n * 256 + co) * H * W + hh * W + ww] = v;
    }
  }
}

// Final conv: Cout = 720 (cls, IS_CLS=true) or 36 (box). Writes permuted:
//   r = rbase + (h*W + w)*9 + a ; out[(n*R + r)*84 + col]
//   cls: co = a*80 + k  -> col k ; box: co = a*4 + j -> col 80 + j
template <bool IS_CLS>
__global__ __launch_bounds__(256) void conv_final(
    const float* __restrict__ x, const float* __restrict__ w,
    const float* __restrict__ b, float* __restrict__ out,
    int H, int W, int tilesX, int Cout, long rbase) {
  __shared__ float xs[CI_CHUNK][10 * 12];
  __shared__ float ws[CI_CHUNK][CO_TILE * 12];
  const int C = 256;
  const long R = 120087;
  const int t = threadIdx.x;
  const int tile = blockIdx.x;
  const int co_base = blockIdx.y * CO_TILE;
  const int n = blockIdx.z;
  const int ty = tile / tilesX, tx = tile - ty * tilesX;
  const int h0 = ty * TS, w0 = tx * TS;
  const int co_l = t >> 3;
  const int row = t & 7;
  const int co = co_base + co_l;

  float acc[8];
#pragma unroll
  for (int i = 0; i < 8; i++) acc[i] = 0.f;

  const float* xn = x + (size_t)n * C * H * W;

  for (int cb = 0; cb < C; cb += CI_CHUNK) {
    for (int i = t; i < CI_CHUNK * 100; i += 256) {
      int ci = i / 100;
      int p = i - ci * 100;
      int r = p / 10;
      int c = p - r * 10;
      int hh = h0 - 1 + r, ww = w0 - 1 + c;
      float v = 0.f;
      if (hh >= 0 && hh < H && ww >= 0 && ww < W)
        v = xn[(size_t)(cb + ci) * H * W + hh * W + ww];
      xs[ci][r * 12 + c] = v;
    }
    for (int i = t; i < CI_CHUNK * CO_TILE * 9; i += 256) {
      int ci = i / (CO_TILE * 9);
      int p = i - ci * (CO_TILE * 9);
      int c2 = p / 9;
      int j = p - c2 * 9;
      int cg = co_base + c2;
      ws[ci][c2 * 12 + j] =
          (cg < Cout) ? w[((size_t)cg * C + cb + ci) * 9 + j] : 0.f;
    }
    __syncthreads();
#pragma unroll
    for (int ci = 0; ci < CI_CHUNK; ci++) {
      const float4* wp = (const float4*)&ws[ci][co_l * 12];
      float4 w0v = wp[0], w1v = wp[1], w2v = wp[2];
      float wr[9] = {w0v.x, w0v.y, w0v.z, w0v.w, w1v.x, w1v.y, w1v.z, w1v.w, w2v.x};
#pragma unroll
      for (int r = 0; r < 3; r++) {
        const float4* xp = (const float4*)&xs[ci][(row + r) * 12];
        float4 a0 = xp[0], a1 = xp[1], a2 = xp[2];
        float xv[12] = {a0.x, a0.y, a0.z, a0.w, a1.x, a1.y,
                        a1.z, a1.w, a2.x, a2.y, a2.z, a2.w};
#pragma unroll
        for (int c = 0; c < 8; c++) {
          acc[c] = fmaf(xv[c + 0], wr[r * 3 + 0], acc[c]);
          acc[c] = fmaf(xv[c + 1], wr[r * 3 + 1], acc[c]);
          acc[c] = fmaf(xv[c + 2], wr[r * 3 + 2], acc[c]);
        }
      }
    }
    __syncthreads();
  }

  if (co < Cout) {
    const float bias = b[co];
    int a, col;
    if (IS_CLS) {
      a = co / 80;
      col = co - a * 80;
    } else {
      a = co >> 2;
      col = 80 + (co & 3);
    }
#pragma unroll
    for (int c = 0; c < 8; c++) {
      int hh = h0 + row, ww = w0 + c;
      if (hh < H && ww < W) {
        long r = rbase + (long)(hh * W + ww) * 9 + a;
        out[((size_t)n * R + r) * 84 + col] = acc[c] + bias;
      }
    }
  }
}

extern "C" void kernel_launch(void* const* d_in, const int* in_sizes, int n_in,
                              void* d_out, int out_size, void* d_ws,
                              size_t ws_size, hipStream_t stream) {
  static const int HW[5][2] = {{100, 100}, {50, 50}, {25, 25}, {13, 13}, {7, 7}};
  const float* f[5];
  for (int i = 0; i < 5; i++) f[i] = (const float*)d_in[i];
  const float *cls_w[4], *cls_b[4], *box_w[4], *box_b[4];
  for (int i = 0; i < 4; i++) {
    cls_w[i] = (const float*)d_in[5 + 2 * i];
    cls_b[i] = (const float*)d_in[6 + 2 * i];
    box_w[i] = (const float*)d_in[13 + 2 * i];
    box_b[i] = (const float*)d_in[14 + 2 * i];
  }
  const float* csw = (const float*)d_in[21];
  const float* csb = (const float*)d_in[22];
  const float* bpw = (const float*)d_in[23];
  const float* bpb = (const float*)d_in[24];
  float* out = (float*)d_out;

  // ping-pong activation buffers: each 2*256*100*100 floats = 20.48 MB
  float* bufA = (float*)d_ws;
  float* bufB = bufA + (size_t)2 * 256 * 100 * 100;

  long rbase = 0;
  for (int l = 0; l < 5; l++) {
    int H = HW[l][0], W = HW[l][1];
    int tilesX = (W + TS - 1) / TS;
    int tilesY = (H + TS - 1) / TS;
    int tiles = tilesX * tilesY;
    dim3 block(256);
    dim3 grid(tiles, 256 / CO_TILE, 2);

    // cls tower
    conv_tower<true><<<grid, block, 0, stream>>>(f[l], cls_w[0], cls_b[0], bufA, H, W, tilesX);
    conv_tower<true><<<grid, block, 0, stream>>>(bufA, cls_w[1], cls_b[1], bufB, H, W, tilesX);
    conv_tower<true><<<grid, block, 0, stream>>>(bufB, cls_w[2], cls_b[2], bufA, H, W, tilesX);
    conv_tower<true><<<grid, block, 0, stream>>>(bufA, cls_w[3], cls_b[3], bufB, H, W, tilesX);
    dim3 gridc(tiles, (720 + CO_TILE - 1) / CO_TILE, 2);
    conv_final<true><<<gridc, block, 0, stream>>>(bufB, csw, csb, out, H, W, tilesX, 720, rbase);

    // box tower
    conv_tower<true><<<grid, block, 0, stream>>>(f[l], box_w[0], box_b[0], bufA, H, W, tilesX);
    conv_tower<true><<<grid, block, 0, stream>>>(bufA, box_w[1], box_b[1], bufB, H, W, tilesX);
    conv_tower<true><<<grid, block, 0, stream>>>(bufB, box_w[2], box_b[2], bufA, H, W, tilesX);
    conv_tower<true><<<grid, block, 0, stream>>>(bufA, box_w[3], box_b[3], bufB, H, W, tilesX);
    dim3 gridb(tiles, (36 + CO_TILE - 1) / CO_TILE, 2);
    conv_final<false><<<gridb, block, 0, stream>>>(bufB, bpw, bpb, out, H, W, tilesX, 36, rbase);

    rbase += (long)H * W * 9;
  }
}

// Round 2
// 690.151 us; speedup vs baseline: 22.9742x; 22.9742x over previous
//
#include <hip/hip_runtime.h>

// RetinaNet head via bf16 MFMA implicit-GEMM.
// Activations: padded NHWC bf16 [n][(tw)][ (H+2)*(W+2) ][256], zero borders.
// Conv block: 64co x 256px (16x16 tile), 4 waves, wave = 64co x 64px as 4x4
// tiles of mfma_f32_16x16x32_bf16. K = 8 chunks(32ci) x 9 taps (LDS offsets).
// LDS: X [quad][384px][8ci] (24.5KB), W [tap][quad][64co][8ci] (36.9KB),
// both staged via global_load_lds dwordx4; all ds_read_b128 lane-consecutive.

typedef __attribute__((ext_vector_type(8))) short short8;
typedef __attribute__((ext_vector_type(4))) float floatx4;

#define LVLTOT 14143  // sum of padded (H+2)(W+2) over 5 levels

__device__ __forceinline__ unsigned short f2bf(float f) {
  unsigned int u = __float_as_uint(f);
  unsigned int r = (u + 0x7fffu + ((u >> 16) & 1u)) >> 16;
  return (unsigned short)r;
}

__device__ __forceinline__ void gload_lds16(const void* g, void* l) {
  __builtin_amdgcn_global_load_lds(
      (const __attribute__((address_space(1))) unsigned int*)g,
      (__attribute__((address_space(3))) unsigned int*)l, 16, 0, 0);
}

// ---- input prep: f[n][256][H][W] fp32 -> X0[n][lvl_px][256] bf16 (padded) ----
__global__ __launch_bounds__(256) void xprep(
    const float* __restrict__ f, unsigned short* __restrict__ x0,
    int H, int W, int Wp, int lvloff) {
  __shared__ float ts[8][33];
  int t = threadIdx.x;
  int w0 = blockIdx.x * 32, h = blockIdx.y;
  int n = blockIdx.z >> 5, cbk = blockIdx.z & 31;
  int cl = t >> 5, wl = t & 31;
  float v = 0.f;
  if (w0 + wl < W)
    v = f[(((size_t)n * 256 + cbk * 8 + cl) * H + h) * W + w0 + wl];
  ts[cl][wl] = v;
  __syncthreads();
  int pi = t >> 3, cj = t & 7;
  if (w0 + pi < W)
    x0[((size_t)n * LVLTOT + lvloff + (size_t)(h + 1) * Wp + (w0 + pi + 1)) * 256 +
       cbk * 8 + cj] = f2bf(ts[cj][pi]);
}

// ---- weight prep: w[Cout][256][9] fp32 -> blob[cb][ch][tap][quad][co64][8] bf16 ----
struct WPArgs {
  const float* src[10];
  unsigned short* dst[10];
  int cout[10];
  int coutp[10];
};
__global__ __launch_bounds__(256) void wprep(WPArgs A) {
  int id = blockIdx.y;
  int idx = blockIdx.x * 256 + threadIdx.x;
  int coutp = A.coutp[id];
  if (idx >= coutp * 256) return;
  int co = idx >> 8, ci = idx & 255;
  const float* w = A.src[id];
  unsigned short* dst = A.dst[id];
  int cb = co >> 6, col = co & 63, chk = ci >> 5, qd = (ci >> 3) & 3, j = ci & 7;
  bool valid = co < A.cout[id];
#pragma unroll
  for (int tap = 0; tap < 9; tap++) {
    float v = valid ? w[((size_t)co * 256 + ci) * 9 + tap] : 0.f;
    dst[((((size_t)(cb * 8 + chk) * 9 + tap) * 4 + qd) * 64 + col) * 8 + j] = f2bf(v);
  }
}

// ---- tile decode (71 tiles over 5 levels) ----
__device__ __forceinline__ void decode_tile(int tile, int& l, int& h0, int& w0,
                                            int& H, int& W, int& Wp, int& loff) {
  const int Ht[5] = {100, 50, 25, 13, 7};
  const int Wpt[5] = {102, 52, 27, 15, 9};
  const int TXt[5] = {7, 4, 2, 1, 1};
  const int LOFFt[5] = {0, 10404, 13108, 13837, 14062};
  int tloc;
  if (tile < 49) { l = 0; tloc = tile; }
  else if (tile < 65) { l = 1; tloc = tile - 49; }
  else if (tile < 69) { l = 2; tloc = tile - 65; }
  else if (tile < 70) { l = 3; tloc = tile - 69; }
  else { l = 4; tloc = 0; }
  H = Ht[l]; W = H; Wp = Wpt[l]; loff = LOFFt[l];
  int ty = tloc / TXt[l], tx = tloc - ty * TXt[l];
  h0 = ty * 16; w0 = tx * 16;
}

// ---- K-loop body shared by tower and final kernels ----
#define CONV_MAIN_LOOP(INP, WBLOB, CB)                                          \
  for (int ch = 0; ch < 8; ch++) {                                              \
    if (ch) __syncthreads();                                                    \
    const unsigned short* wsrc = (WBLOB) + ((size_t)((CB)*8 + ch)) * 18432;     \
    _Pragma("unroll")                                                           \
    for (int i = 0; i < 9; i++)                                                 \
      gload_lds16(wsrc + i * 2048 + wv * 512 + lane * 8,                        \
                  lds_w + i * 2048 + wv * 512);                                 \
    _Pragma("unroll")                                                           \
    for (int g = 0; g < 6; g++) {                                               \
      int px = g * 64 + lane;                                                   \
      int r = px / 18, c = px - r * 18;                                         \
      int hh = h0 + r; if (hh > Hpad - 1) hh = Hpad - 1;                        \
      int ww = w0 + c; if (ww > Wp - 1) ww = Wp - 1;                            \
      gload_lds16((INP) + ((size_t)hh * Wp + ww) * 256 + ch * 32 + wv * 8,      \
                  lds_x + wv * 3072 + g * 512);                                 \
    }                                                                           \
    __syncthreads();                                                            \
    const short8* xw = (const short8*)lds_w;                                    \
    const short8* xx = (const short8*)lds_x;                                    \
    _Pragma("unroll")                                                           \
    for (int tap = 0; tap < 9; tap++) {                                         \
      const int tdy = tap / 3, tdx = tap - 3 * (tap / 3);                       \
      short8 bfr[4];                                                            \
      _Pragma("unroll")                                                         \
      for (int rr = 0; rr < 4; rr++)                                            \
        bfr[rr] = xx[q * 384 + (wv * 4 + rr + tdy) * 18 + n16 + tdx];           \
      _Pragma("unroll")                                                         \
      for (int cc = 0; cc < 4; cc++) {                                          \
        short8 afr = xw[(tap * 4 + q) * 64 + cc * 16 + n16];                    \
        _Pragma("unroll")                                                       \
        for (int rr = 0; rr < 4; rr++)                                          \
          acc[cc][rr] = __builtin_amdgcn_mfma_f32_16x16x32_bf16(                \
              afr, bfr[rr], acc[cc][rr], 0, 0, 0);                              \
      }                                                                         \
    }                                                                           \
  }

// ---- tower conv layer (bf16 in -> bf16 out, +bias, ReLU) ----
__global__ __launch_bounds__(256, 2) void conv_tower_mfma(
    const unsigned short* __restrict__ xin, unsigned short* __restrict__ xout,
    const unsigned short* __restrict__ wblob_cls,
    const unsigned short* __restrict__ wblob_box,
    const float* __restrict__ bias_cls, const float* __restrict__ bias_box,
    int in_n_stride, int in_tw_stride) {
  __shared__ __align__(16) unsigned short lds_w[18432];
  __shared__ __align__(16) unsigned short lds_x[12288];
  const int t = threadIdx.x, lane = t & 63, wv = t >> 6;
  const int q = lane >> 4, n16 = lane & 15;
  int l, h0, w0, H, W, Wp, loff;
  decode_tile(blockIdx.x, l, h0, w0, H, W, Wp, loff);
  const int Hpad = H + 2;
  const int cb = blockIdx.y;
  const int n = blockIdx.z >> 1, tw = blockIdx.z & 1;
  const unsigned short* wblob = tw ? wblob_box : wblob_cls;
  const float* bias = tw ? bias_box : bias_cls;
  const unsigned short* inp =
      xin + ((size_t)n * in_n_stride + (size_t)tw * in_tw_stride + loff) * 256;
  unsigned short* outp = xout + ((size_t)(n * 2 + tw) * LVLTOT + loff) * 256;

  floatx4 acc[4][4];
#pragma unroll
  for (int i = 0; i < 4; i++)
#pragma unroll
    for (int jj = 0; jj < 4; jj++) acc[i][jj] = (floatx4){0.f, 0.f, 0.f, 0.f};

  CONV_MAIN_LOOP(inp, wblob, cb)

  // epilogue: +bias, relu, bf16, store 4 consecutive channels (8B) per lane
#pragma unroll
  for (int cc = 0; cc < 4; cc++) {
    floatx4 bb = *(const floatx4*)(bias + cb * 64 + cc * 16 + q * 4);
#pragma unroll
    for (int rr = 0; rr < 4; rr++) {
      int h = h0 + wv * 4 + rr;
      int w_ = w0 + n16;
      if (h < H && w_ < W) {
        unsigned short pk[4];
#pragma unroll
        for (int rg = 0; rg < 4; rg++)
          pk[rg] = f2bf(fmaxf(acc[cc][rr][rg] + bb[rg], 0.f));
        size_t base =
            ((size_t)(h + 1) * Wp + (w_ + 1)) * 256 + cb * 64 + cc * 16 + q * 4;
        *(unsigned long long*)(outp + base) = *(unsigned long long*)pk;
      }
    }
  }
}

// ---- final conv (bf16 in -> permuted fp32 out) ----
template <bool IS_CLS>
__global__ __launch_bounds__(256, 2) void conv_final_mfma(
    const unsigned short* __restrict__ xin, float* __restrict__ out,
    const unsigned short* __restrict__ wblob, const float* __restrict__ bias) {
  __shared__ __align__(16) unsigned short lds_w[18432];
  __shared__ __align__(16) unsigned short lds_x[12288];
  const int t = threadIdx.x, lane = t & 63, wv = t >> 6;
  const int q = lane >> 4, n16 = lane & 15;
  int l, h0, w0, H, W, Wp, loff;
  decode_tile(blockIdx.x, l, h0, w0, H, W, Wp, loff);
  const int Hpad = H + 2;
  const int cb = blockIdx.y;
  const int n = blockIdx.z;
  const int tw = IS_CLS ? 0 : 1;
  const int Cout = IS_CLS ? 720 : 36;
  const int RB[5] = {0, 90000, 112500, 118125, 119646};
  const unsigned short* inp = xin + ((size_t)(n * 2 + tw) * LVLTOT + loff) * 256;

  floatx4 acc[4][4];
#pragma unroll
  for (int i = 0; i < 4; i++)
#pragma unroll
    for (int jj = 0; jj < 4; jj++) acc[i][jj] = (floatx4){0.f, 0.f, 0.f, 0.f};

  CONV_MAIN_LOOP(inp, wblob, cb)

#pragma unroll
  for (int cc = 0; cc < 4; cc++) {
    int co0 = cb * 64 + cc * 16 + q * 4;
    if (co0 >= Cout) continue;
    floatx4 bb = *(const floatx4*)(bias + co0);
    int a = IS_CLS ? (co0 / 80) : (co0 >> 2);
    int col0 = IS_CLS ? (co0 - a * 80) : 80;
#pragma unroll
    for (int rr = 0; rr < 4; rr++) {
      int h = h0 + wv * 4 + rr;
      int w_ = w0 + n16;
      if (h < H && w_ < W) {
        size_t ridx = (size_t)RB[l] + ((size_t)h * W + w_) * 9 + a;
        floatx4 v;
#pragma unroll
        for (int rg = 0; rg < 4; rg++) v[rg] = acc[cc][rr][rg] + bb[rg];
        *(floatx4*)(out + ((size_t)n * 120087 + ridx) * 84 + col0) = v;
      }
    }
  }
}

extern "C" void kernel_launch(void* const* d_in, const int* in_sizes, int n_in,
                              void* d_out, int out_size, void* d_ws,
                              size_t ws_size, hipStream_t stream) {
  // ws layout (bytes):
  //   bufB   [0, 28964864)   (X0 aliased into its upper half: layer2 output
  //   X0     [14482432, 28964864)          overwrites X0 only after it's dead)
  //   bufA   [28964864, 57929728)
  //   tower blobs 8 x 1179648 at 57929728  (cls0..3, box0..3)
  //   cls final blob 3538944 at 67366912
  //   box final blob  294912 at 70905856
  char* ws = (char*)d_ws;
  unsigned short* bufB = (unsigned short*)(ws);
  unsigned short* X0 = (unsigned short*)(ws + 14482432);
  unsigned short* bufA = (unsigned short*)(ws + 28964864);
  unsigned short* tb[8];
  for (int i = 0; i < 8; i++)
    tb[i] = (unsigned short*)(ws + 57929728 + (size_t)i * 1179648);
  unsigned short* fb_cls = (unsigned short*)(ws + 67366912);
  unsigned short* fb_box = (unsigned short*)(ws + 70905856);

  const float* f[5];
  for (int i = 0; i < 5; i++) f[i] = (const float*)d_in[i];
  float* out = (float*)d_out;

  // zero activation buffers (borders must be 0; interiors get overwritten)
  hipMemsetAsync(ws, 0, 57929728, stream);

  // input prep per level
  const int Ht[5] = {100, 50, 25, 13, 7};
  const int Wpt[5] = {102, 52, 27, 15, 9};
  const int LOFFt[5] = {0, 10404, 13108, 13837, 14062};
  for (int l = 0; l < 5; l++) {
    dim3 g((Ht[l] + 31) / 32, Ht[l], 64);
    xprep<<<g, 256, 0, stream>>>(f[l], X0, Ht[l], Ht[l], Wpt[l], LOFFt[l]);
  }

  // weight prep (all 10 tensors in one dispatch)
  WPArgs wa;
  for (int i = 0; i < 4; i++) {
    wa.src[i] = (const float*)d_in[5 + 2 * i];      // cls_w0..3
    wa.src[4 + i] = (const float*)d_in[13 + 2 * i]; // box_w0..3
    wa.dst[i] = tb[i];
    wa.dst[4 + i] = tb[4 + i];
    wa.cout[i] = wa.cout[4 + i] = 256;
    wa.coutp[i] = wa.coutp[4 + i] = 256;
  }
  wa.src[8] = (const float*)d_in[21]; wa.dst[8] = fb_cls;
  wa.cout[8] = 720; wa.coutp[8] = 768;
  wa.src[9] = (const float*)d_in[23]; wa.dst[9] = fb_box;
  wa.cout[9] = 36; wa.coutp[9] = 64;
  wprep<<<dim3(768, 10), 256, 0, stream>>>(wa);

  const float* cls_b[4], * box_b[4];
  for (int i = 0; i < 4; i++) {
    cls_b[i] = (const float*)d_in[6 + 2 * i];
    box_b[i] = (const float*)d_in[14 + 2 * i];
  }

  dim3 gt(71, 4, 4);
  // layer 1: X0 (shared by towers) -> bufA
  conv_tower_mfma<<<gt, 256, 0, stream>>>(X0, bufA, tb[0], tb[4], cls_b[0],
                                          box_b[0], LVLTOT, 0);
  // layer 2: bufA -> bufB (overwrites dead X0)
  conv_tower_mfma<<<gt, 256, 0, stream>>>(bufA, bufB, tb[1], tb[5], cls_b[1],
                                          box_b[1], 2 * LVLTOT, LVLTOT);
  // layer 3: bufB -> bufA
  conv_tower_mfma<<<gt, 256, 0, stream>>>(bufB, bufA, tb[2], tb[6], cls_b[2],
                                          box_b[2], 2 * LVLTOT, LVLTOT);
  // layer 4: bufA -> bufB
  conv_tower_mfma<<<gt, 256, 0, stream>>>(bufA, bufB, tb[3], tb[7], cls_b[3],
                                          box_b[3], 2 * LVLTOT, LVLTOT);

  // finals
  conv_final_mfma<true><<<dim3(71, 12, 2), 256, 0, stream>>>(
      bufB, out, fb_cls, (const float*)d_in[22]);
  conv_final_mfma<false><<<dim3(71, 1, 2), 256, 0, stream>>>(
      bufB, out, fb_box, (const float*)d_in[24]);
}